// Round 13
// baseline (466.315 us; speedup 1.0000x reference)
//
#include <hip/hip_runtime.h>
#include <cstdint>
#include <cstddef>

// VQ-VAE vector quantizer forward, MI355X.
// B=65536 rows, K=4096 codes, D=256.
// Outputs (flat float32): z_q_st[B*D] | vq_loss | perplexity | indices[B] | diversity_loss

#define NROWS     65536
#define NCODES    4096
#define DDIM      256
#define CAND_CAP  24
#define UMARGIN   1.0f    // u-space: d-margin 2.0 / 2
#define USKIP     8.5f    // u-space: d-skip 17 / 2 (dropped soft terms < e^-17, Z>=1)

typedef _Float16 half8 __attribute__((ext_vector_type(8)));
typedef _Float16 half4 __attribute__((ext_vector_type(4)));
typedef float    f32x4 __attribute__((ext_vector_type(4)));

// ---- workspace layout (bytes) ----
#define WS_BINCNT   0u          // 4096*4    = 16384    (zeroed)
#define WS_ZERO_END 16384u
#define WS_CANDCNT  16384u      // 65536*4   = 262144   (plain-written by sweep, no zero)
#define WS_SPART    278528u     // 512*4096*4 = 8388608 (fully written by sweep)
#define WS_EF16     8667136u    // 4096*256*2 = 2097152
#define WS_EE       10764288u   // 4096*4     = 16384
#define WS_ROWD     10780672u   // 65536*4    = 262144
#define WS_CANDIDX  11042816u   // 65536*24*4 = 6291456 (aliased as tm[4096] dbl after refine)
#define WS_TE       17334272u   // 4096*8     = 32768
#define WS_TP       17367040u   // 4096*8     = 32768
#define WS_END      17399808u

__device__ __forceinline__ void gload_lds16(const void* g, void* lds) {
    __builtin_amdgcn_global_load_lds(
        (const __attribute__((address_space(1))) unsigned int*)g,
        (__attribute__((address_space(3))) unsigned int*)lds, 16, 0, 0);
}

// ---------------- prep (embedding only): fp32 -> fp16 copy + row norms ----------------
__global__ __launch_bounds__(256)
void prep_kernel(const float* __restrict__ src, _Float16* __restrict__ dst,
                 float* __restrict__ norms)
{
    const int tid = threadIdx.x;
    const int w = tid >> 6, l = tid & 63;
    const int row = blockIdx.x * 4 + w;
    const float4 v = *(const float4*)(src + (size_t)row * DDIM + l * 4);
    half4 h;
    h[0] = (_Float16)v.x; h[1] = (_Float16)v.y;
    h[2] = (_Float16)v.z; h[3] = (_Float16)v.w;
    *(half4*)(dst + (size_t)row * DDIM + l * 4) = h;
    double s = (double)v.x * v.x + (double)v.y * v.y
             + (double)v.z * v.z + (double)v.w * v.w;
#pragma unroll
    for (int off = 1; off < 64; off <<= 1) s += __shfl_xor(s, off, 64);
    if (l == 0) norms[row] = (float)s;
}

// ---- epilogue helpers (register-only / rare LDS ops; operate on PREVIOUS step's acc) ----
__device__ __forceinline__ void epi_phase0(const f32x4 (&acc)[2][4],
                                           float (&pmx)[8], float (&pZ)[8])
{
#pragma unroll
    for (int fr = 0; fr < 2; ++fr)
#pragma unroll
    for (int reg = 0; reg < 4; ++reg) {
        const int ri = fr * 4 + reg;
        const float u0 = acc[fr][0][reg];
        const float u1 = acc[fr][1][reg];
        const float u2 = acc[fr][2][reg];
        const float u3 = acc[fr][3][reg];
        const float mloc = fmaxf(fmaxf(u0, u1), fmaxf(u2, u3));
        float m = pmx[ri];
        if (mloc > m - USKIP) {   // dropped terms < e^-17, Z >= 1
            if (mloc > m) { pZ[ri] *= __expf(2.0f * (m - mloc)); m = mloc; pmx[ri] = m; }
            pZ[ri] += __expf(2.0f * (u0 - m)) + __expf(2.0f * (u1 - m))
                    + __expf(2.0f * (u2 - m)) + __expf(2.0f * (u3 - m));
        }
    }
}

__device__ __forceinline__ void epi_merge(float (&pmx)[8], float (&pZ)[8])
{
    // merge (max,Z) across the 16 lanes sharing each row; pZ := 1/Z
#pragma unroll
    for (int ri = 0; ri < 8; ++ri) {
        float m = pmx[ri], Zv = pZ[ri];
#pragma unroll
        for (int off = 1; off < 16; off <<= 1) {
            const float mo = __shfl_xor(m, off, 64);
            const float Zo = __shfl_xor(Zv, off, 64);
            const float mn = fmaxf(m, mo);
            Zv = Zv * __expf(2.0f * (m - mn)) + Zo * __expf(2.0f * (mo - mn));
            m = mn;
        }
        pmx[ri] = m;
        pZ[ri] = 1.0f / Zv;
    }
}

__device__ __forceinline__ void epi_phase1(const f32x4 (&acc)[2][4],
                                           const float (&pmx)[8], const float (&pZ)[8],
                                           int (&bcnt)[8], float* __restrict__ Sl,
                                           int* __restrict__ cand_idx, const int nt,
                                           const int row0, const int w,
                                           const int lg, const int lc, const int l)
{
    float sp[4] = {0.f, 0.f, 0.f, 0.f};
#pragma unroll
    for (int fr = 0; fr < 2; ++fr)
#pragma unroll
    for (int reg = 0; reg < 4; ++reg) {
        const int ri = fr * 4 + reg;
        const float m = pmx[ri], iz = pZ[ri];   // pZ holds 1/Z in phase 1
        const float u0 = acc[fr][0][reg];
        const float u1 = acc[fr][1][reg];
        const float u2 = acc[fr][2][reg];
        const float u3 = acc[fr][3][reg];
        // candidates: ballot + prefix-popcount slots (uniform participation per cf)
#pragma unroll
        for (int cf = 0; cf < 4; ++cf) {
            const float u = acc[fr][cf][reg];
            const bool hit = (u >= m - UMARGIN);   // m = exact phase-0 row max
            const unsigned long long mk = __ballot(hit);
            if (mk) {                              // uniform branch, rare
                const unsigned grp = (unsigned)((mk >> (lg * 16)) & 0xFFFFull);
                const int slot = bcnt[ri] + __popc(grp & ((1u << lc) - 1u));
                if (hit && slot < CAND_CAP) {
                    const int rg_ = row0 + w * 32 + fr * 16 + lg * 4 + reg;
                    cand_idx[(size_t)rg_ * CAND_CAP + slot] = nt * 64 + cf * 16 + lc;
                }
                bcnt[ri] += __popc(grp);
            }
        }
        // soft partials: one group-max guard (dropped terms < e^-17 with Z >= 1)
        const float umax = fmaxf(fmaxf(u0, u1), fmaxf(u2, u3));
        if (umax >= m - USKIP) {
            sp[0] += __expf(2.0f * (u0 - m)) * iz;
            sp[1] += __expf(2.0f * (u1 - m)) * iz;
            sp[2] += __expf(2.0f * (u2 - m)) * iz;
            sp[3] += __expf(2.0f * (u3 - m)) * iz;
        }
    }
#pragma unroll
    for (int cf = 0; cf < 4; ++cf) {   // sum across lg, then LDS accumulate
        float v = sp[cf];
        v += __shfl_xor(v, 16, 64);
        v += __shfl_xor(v, 32, 64);
        if (l < 16) atomicAdd(&Sl[nt * 64 + cf * 16 + l], v);
    }
}

// ---- one pipeline step: stage(s+1) | MFMA(s)->accC | EPI(s-1) on accP | barrier ----
__device__ __forceinline__ void sweep_step(
    const int s, f32x4 (&accC)[2][4], f32x4 (&accP)[2][4],
    float (&eevc)[4], float (&eevn)[4],
    const half8 (&af)[2][8], char* __restrict__ blb, const char* __restrict__ efb,
    const float* __restrict__ ee, const int (&soff)[8],
    float (&pmx)[8], float (&pZ)[8], int (&bcnt)[8],
    float* __restrict__ Sl, int* __restrict__ cand_idx,
    const int row0, const int w, const int l, const int lg, const int lc)
{
    const int cur = s & 1;
    const int nnt = (s + 1) & 63;

    // next-step eev: issued now, consumed after the barrier (never waited mid-loop)
#pragma unroll
    for (int cf = 0; cf < 4; ++cf) eevn[cf] = ee[nnt * 64 + cf * 16 + lc];

    if (s < 127) {                      // stage next sub-tile into other buffer
        const char* src = efb + ((size_t)nnt << 15);
        char* dst = blb + (cur ^ 1) * 32768;
#pragma unroll
        for (int it = 0; it < 8; ++it)
            gload_lds16(src + soff[it], dst + (w * 8 + it) * 1024);
    }

    // acc init: -0.5*||e||^2  ->  MFMA output u = z.e - ||e||^2/2 = -d'/2
#pragma unroll
    for (int cf = 0; cf < 4; ++cf) {
        const float eh = -0.5f * eevc[cf];
        accC[0][cf] = (f32x4){eh, eh, eh, eh};
        accC[1][cf] = (f32x4){eh, eh, eh, eh};
    }

    // lane-linear B reads (conflict-free), immediate offsets
    const char* bb = blb + cur * 32768 + (l << 4);
#pragma unroll
    for (int ksl = 0; ksl < 8; ++ksl) {
#pragma unroll
        for (int cf = 0; cf < 4; ++cf) {
            const half8 b = *(const half8*)(bb + (ksl * 4 + cf) * 1024);
            accC[0][cf] = __builtin_amdgcn_mfma_f32_16x16x32_f16(af[0][ksl], b, accC[0][cf], 0, 0, 0);
            accC[1][cf] = __builtin_amdgcn_mfma_f32_16x16x32_f16(af[1][ksl], b, accC[1][cf], 0, 0, 0);
        }
    }

    // deferred epilogue of step s-1: independent of this step's MFMAs -> overlaps
    if (s >= 1) {
        const int sprev = s - 1;
        if (sprev < 64) {
            epi_phase0(accP, pmx, pZ);
            if (sprev == 63) epi_merge(pmx, pZ);   // before first phase-1 epi (at s=65)
        } else {
            epi_phase1(accP, pmx, pZ, bcnt, Sl, cand_idx, sprev & 63, row0, w, lg, lc, l);
        }
    }

    __syncthreads();   // sole vmcnt drain: staging + eev issued a full phase ago
#pragma unroll
    for (int cf = 0; cf < 4; ++cf) eevc[cf] = eevn[cf];
}

// ---------------- fused two-phase distance sweep, software-pipelined ----------------
// r7 geometry: 4 waves, wave w owns rows w*32..+31 for ALL codes. B: 64-code x K=256
// sub-tiles, 2 x 32 KB LDS dbuf, FRAGMENT-MAJOR (conflict-free lane-linear
// ds_read_b128; staged via global_load_lds with pre-permuted per-lane source).
// u-space acc init; eev one step ahead; ballot candidates; NO setprio (m190).
// NEW (T15-style): the epilogue runs ONE STEP BEHIND the MFMA, on a ping-pong
// acc pair (accA even / accB odd, named statically - rule #20), so its VALU/trans
// work overlaps the next step's ds_read+MFMA instead of serializing after it.
// Math sequence unchanged -> outputs bitwise identical to the r12 kernel.
__global__ __launch_bounds__(256, 2)
void sweep_fused_kernel(const float* __restrict__ z, const _Float16* __restrict__ ef,
                        const float* __restrict__ ee, float* __restrict__ Spart,
                        int* __restrict__ cand_cnt, int* __restrict__ cand_idx)
{
    __shared__ _Float16 Bl[2][64 * 256];   // 2 x 32 KB, fragment-major
    __shared__ float Sl[NCODES];           // 16 KB soft accumulator

    const int tid = threadIdx.x;
    const int w = tid >> 6, l = tid & 63;
    const int lg = l >> 4, lc = l & 15;
    const int row0 = blockIdx.x * 128;

    // A fragments: row = row0 + w*32 + fr*16 + lc, k = ksl*32 + lg*8 .. +8 (f32 -> f16)
    half8 af[2][8];
#pragma unroll
    for (int fr = 0; fr < 2; ++fr)
#pragma unroll
    for (int ksl = 0; ksl < 8; ++ksl) {
        const float* zp = z + (size_t)(row0 + w * 32 + fr * 16 + lc) * DDIM + ksl * 32 + lg * 8;
        const float4 v0 = *(const float4*)zp;
        const float4 v1 = *(const float4*)(zp + 4);
        half8 h;
        h[0] = (_Float16)v0.x; h[1] = (_Float16)v0.y; h[2] = (_Float16)v0.z; h[3] = (_Float16)v0.w;
        h[4] = (_Float16)v1.x; h[5] = (_Float16)v1.y; h[6] = (_Float16)v1.z; h[7] = (_Float16)v1.w;
        af[fr][ksl] = h;
    }

    for (int i = tid; i < NCODES; i += 256) Sl[i] = 0.0f;

    // staging: instr it_g = w*8+it = slot (ksl=it_g>>2, cf=it_g&3); lane l fetches
    // global code cf*16+lc at kbytes ksl*64+lg*16 -> LDS it_g*1024 + l*16 (linear).
    int soff[8];
#pragma unroll
    for (int it = 0; it < 8; ++it) {
        const int it_g = w * 8 + it;
        const int ksl = it_g >> 2, cf = it_g & 3;
        soff[it] = (cf * 16 + lc) * 512 + ksl * 64 + lg * 16;
    }
    const char* efb = (const char*)ef;
    char* blb = (char*)&Bl[0][0];

    float pmx[8], pZ[8];
#pragma unroll
    for (int i = 0; i < 8; ++i) { pmx[i] = -1e30f; pZ[i] = 0.0f; }
    int bcnt[8];
#pragma unroll
    for (int i = 0; i < 8; ++i) bcnt[i] = 0;

    // prologue: eev for tile 0 + stage tile 0 into buffer 0
    float eevc[4], eevn[4];
#pragma unroll
    for (int cf = 0; cf < 4; ++cf) eevc[cf] = ee[cf * 16 + lc];
#pragma unroll
    for (int it = 0; it < 8; ++it)
        gload_lds16(efb + soff[it], blb + (w * 8 + it) * 1024);
    __syncthreads();

    f32x4 accA[2][4], accB[2][4];

    // pipeline: s=0 (accA, no epi); pairs s=2sp+1 (accB) / s=2sp+2 (accA); s=127 (accB)
    sweep_step(0, accA, accB, eevc, eevn, af, blb, efb, ee, soff,
               pmx, pZ, bcnt, Sl, cand_idx, row0, w, l, lg, lc);
    for (int sp = 0; sp < 63; ++sp) {
        sweep_step(2 * sp + 1, accB, accA, eevc, eevn, af, blb, efb, ee, soff,
                   pmx, pZ, bcnt, Sl, cand_idx, row0, w, l, lg, lc);
        sweep_step(2 * sp + 2, accA, accB, eevc, eevn, af, blb, efb, ee, soff,
                   pmx, pZ, bcnt, Sl, cand_idx, row0, w, l, lg, lc);
    }
    sweep_step(127, accB, accA, eevc, eevn, af, blb, efb, ee, soff,
               pmx, pZ, bcnt, Sl, cand_idx, row0, w, l, lg, lc);
    // drain: epilogue of the final step (s=127, accB, phase 1, nt=63)
    epi_phase1(accB, pmx, pZ, bcnt, Sl, cand_idx, 63, row0, w, lg, lc, l);
    __syncthreads();   // all Sl atomics visible before writeout

    // final: per-row candidate counts (plain stores; every row covered once)
    if (lc == 0) {
#pragma unroll
        for (int fr = 0; fr < 2; ++fr)
#pragma unroll
        for (int reg = 0; reg < 4; ++reg)
            cand_cnt[row0 + w * 32 + fr * 16 + lg * 4 + reg] = bcnt[fr * 4 + reg];
    }

    for (int i = tid; i < NCODES; i += 256)
        Spart[(size_t)blockIdx.x * NCODES + i] = Sl[i];
}

// ---------------- refine: exact fp64 argmin over candidates ----------------
__global__ __launch_bounds__(256)
void refine_kernel(const float* __restrict__ z, const float* __restrict__ emb,
                   const int* __restrict__ cand_cnt, const int* __restrict__ cand_idx,
                   float* __restrict__ out_zq, float* __restrict__ out_idx,
                   unsigned int* __restrict__ bincnt, float* __restrict__ rowD)
{
    const int tid = threadIdx.x;
    const int w = tid >> 6, l = tid & 63;
    const int row = blockIdx.x * 4 + w;
    const float4 zv = *(const float4*)(z + (size_t)row * DDIM + l * 4);
    const double z0 = zv.x, z1 = zv.y, z2 = zv.z, z3 = zv.w;
    const int craw = cand_cnt[row];
    const int cnt = craw < 1 ? 1 : (craw > CAND_CAP ? CAND_CAP : craw);
    double dmin = 1e300; int kmin = 0;
    for (int c = 0; c < cnt; ++c) {
        int k = (craw < 1) ? 0 : cand_idx[(size_t)row * CAND_CAP + c];
        k &= (NCODES - 1);
        const float4 ev = *(const float4*)(emb + (size_t)k * DDIM + l * 4);
        const double t0 = z0 - ev.x, t1 = z1 - ev.y, t2 = z2 - ev.z, t3 = z3 - ev.w;
        double s = t0 * t0 + t1 * t1 + t2 * t2 + t3 * t3;
#pragma unroll
        for (int off = 1; off < 64; off <<= 1) s += __shfl_xor(s, off, 64);
        if (s < dmin || (s == dmin && k < kmin)) { dmin = s; kmin = k; }
    }
    const float4 bv = *(const float4*)(emb + (size_t)kmin * DDIM + l * 4);
    *(float4*)(out_zq + (size_t)row * DDIM + l * 4) = bv;   // z + sg(zq - z) == zq
    if (l == 0) {
        out_idx[row] = (float)kmin;
        atomicAdd(&bincnt[kmin], 1u);
        rowD[row] = (float)dmin;                             // dmin == ||z - zq||^2
    }
}

// ---------------- reductions ----------------
__global__ __launch_bounds__(256)
void reduce1_kernel(const float* __restrict__ Spart, const unsigned int* __restrict__ bincnt,
                    const float* __restrict__ rowD,
                    double* __restrict__ te, double* __restrict__ tp, double* __restrict__ tm)
{
    const int k = blockIdx.x * 256 + threadIdx.x;   // grid 16 -> k < 4096
    double s = 0.0;
#pragma unroll 8
    for (int wg = 0; wg < 512; ++wg) s += (double)Spart[(size_t)wg * NCODES + k];
    const double avg = s * (1.0 / 65536.0);
    te[k] = avg * log(avg + 1e-10);
    const double ap = (double)bincnt[k] * (1.0 / 65536.0);
    tp[k] = ap * log(ap + 1e-10);
    double dm = 0.0;
#pragma unroll
    for (int j = 0; j < 16; ++j) dm += (double)rowD[k * 16 + j];
    tm[k] = dm;
}

__global__ __launch_bounds__(256)
void reduce2_kernel(const double* __restrict__ te, const double* __restrict__ tp,
                    const double* __restrict__ tm, float* __restrict__ out)
{
    __shared__ double sa[256], sb[256], sc[256];
    const int tid = threadIdx.x;
    double a = 0.0, b = 0.0, c = 0.0;
    for (int i = tid; i < NCODES; i += 256) { a += te[i]; b += tp[i]; c += tm[i]; }
    sa[tid] = a; sb[tid] = b; sc[tid] = c;
    __syncthreads();
    for (int s = 128; s > 0; s >>= 1) {
        if (tid < s) { sa[tid] += sa[tid + s]; sb[tid] += sb[tid + s]; sc[tid] += sc[tid + s]; }
        __syncthreads();
    }
    if (tid == 0) {
        const double entropy    = -sa[0];
        const double diversity  = log(4096.0) - entropy;
        const double perplexity = exp(-sb[0]);
        const double mse        = sc[0] * (1.0 / 16777216.0);
        const double vq         = 1.25 * mse + 0.1 * diversity;  // 0.25*c + e + 0.1*d, c==e
        out[16777216] = (float)vq;
        out[16777217] = (float)perplexity;
        out[16842754] = (float)diversity;
    }
}

extern "C" void kernel_launch(void* const* d_in, const int* in_sizes, int n_in,
                              void* d_out, int out_size, void* d_ws, size_t ws_size,
                              hipStream_t stream)
{
    const float* z   = (const float*)d_in[0];
    const float* emb = (const float*)d_in[1];
    float* out = (float*)d_out;
    char* ws = (char*)d_ws;
    if (ws_size < (size_t)WS_END) return;   // need ~17.4 MB scratch

    unsigned int* bincnt   = (unsigned int*)(ws + WS_BINCNT);
    int*          cand_cnt = (int*)(ws + WS_CANDCNT);
    float*        Spart    = (float*)(ws + WS_SPART);
    _Float16*     ef16     = (_Float16*)(ws + WS_EF16);
    float*        ee       = (float*)(ws + WS_EE);
    float*        rowD     = (float*)(ws + WS_ROWD);
    int*          cand_idx = (int*)(ws + WS_CANDIDX);
    double*       te       = (double*)(ws + WS_TE);
    double*       tp       = (double*)(ws + WS_TP);
    double*       tm       = (double*)(ws + WS_CANDIDX);  // cand_idx dead after refine

    hipMemsetAsync(d_ws, 0, WS_ZERO_END, stream);   // bincnt only (16 KB)
    hipLaunchKernelGGL(prep_kernel, dim3(NCODES / 4), dim3(256), 0, stream, emb, ef16, ee);
    hipLaunchKernelGGL(sweep_fused_kernel, dim3(NROWS / 128), dim3(256), 0, stream,
                       z, ef16, ee, Spart, cand_cnt, cand_idx);
    hipLaunchKernelGGL(refine_kernel, dim3(NROWS / 4), dim3(256), 0, stream,
                       z, emb, cand_cnt, cand_idx, out, out + 16777218, bincnt, rowD);
    hipLaunchKernelGGL(reduce1_kernel, dim3(16), dim3(256), 0, stream, Spart, bincnt, rowD, te, tp, tm);
    hipLaunchKernelGGL(reduce2_kernel, dim3(1), dim3(256), 0, stream, te, tp, tm, out);
}

// Round 14
// 461.753 us; speedup vs baseline: 1.0099x; 1.0099x over previous
//
#include <hip/hip_runtime.h>
#include <cstdint>
#include <cstddef>

// VQ-VAE vector quantizer forward, MI355X.
// B=65536 rows, K=4096 codes, D=256.
// Outputs (flat float32): z_q_st[B*D] | vq_loss | perplexity | indices[B] | diversity_loss

#define NROWS     65536
#define NCODES    4096
#define DDIM      256
#define CAND_CAP  24
#define UMARGIN   1.0f    // u-space: d-margin 2.0 / 2
#define USKIP     8.5f    // u-space: d-skip 17 / 2 (dropped soft terms < e^-17, Z>=1)

typedef _Float16 half8 __attribute__((ext_vector_type(8)));
typedef _Float16 half4 __attribute__((ext_vector_type(4)));
typedef float    f32x4 __attribute__((ext_vector_type(4)));

// ---- workspace layout (bytes) ----
#define WS_BINCNT   0u          // 4096*4    = 16384    (zeroed)
#define WS_ZERO_END 16384u
#define WS_CANDCNT  16384u      // 65536*4   = 262144   (plain-written by sweep, no zero)
#define WS_SPART    278528u     // 512*4096*4 = 8388608 (fully written by sweep)
#define WS_EF16     8667136u    // 4096*256*2 = 2097152
#define WS_EE       10764288u   // 4096*4     = 16384
#define WS_ROWD     10780672u   // 65536*4    = 262144
#define WS_CANDIDX  11042816u   // 65536*24*4 = 6291456 (aliased as tm[4096] dbl after refine)
#define WS_TE       17334272u   // 4096*8     = 32768
#define WS_TP       17367040u   // 4096*8     = 32768
#define WS_END      17399808u

__device__ __forceinline__ void gload_lds16(const void* g, void* lds) {
    __builtin_amdgcn_global_load_lds(
        (const __attribute__((address_space(1))) unsigned int*)g,
        (__attribute__((address_space(3))) unsigned int*)lds, 16, 0, 0);
}

// ---------------- prep (embedding only): fp32 -> fp16 copy + row norms ----------------
__global__ __launch_bounds__(256)
void prep_kernel(const float* __restrict__ src, _Float16* __restrict__ dst,
                 float* __restrict__ norms)
{
    const int tid = threadIdx.x;
    const int w = tid >> 6, l = tid & 63;
    const int row = blockIdx.x * 4 + w;
    const float4 v = *(const float4*)(src + (size_t)row * DDIM + l * 4);
    half4 h;
    h[0] = (_Float16)v.x; h[1] = (_Float16)v.y;
    h[2] = (_Float16)v.z; h[3] = (_Float16)v.w;
    *(half4*)(dst + (size_t)row * DDIM + l * 4) = h;
    double s = (double)v.x * v.x + (double)v.y * v.y
             + (double)v.z * v.z + (double)v.w * v.w;
#pragma unroll
    for (int off = 1; off < 64; off <<= 1) s += __shfl_xor(s, off, 64);
    if (l == 0) norms[row] = (float)s;
}

// ---------------- fused two-phase distance sweep, split half-chains ----------------
// r7/r12 geometry: 4 waves, wave w owns rows w*32..+31 for ALL codes. B: 64-code x
// K=256 sub-tiles, 2 x 32 KB LDS dbuf, FRAGMENT-MAJOR (conflict-free lane-linear
// ds_read_b128; staged via global_load_lds with pre-permuted per-lane source).
// u-space acc init; eev one step ahead; ballot candidates; NO setprio (m190).
// NEW: each step is TWO INDEPENDENT half-chains — chain A (cf 0,1: 16 ds_reads ->
// 32 MFMAs -> epiA) and chain B (cf 2,3). Source order stage|chainA|chainB|epiA|
// epiB|barrier: chain B's reads/MFMAs cover chain A's MFMA->VALU hazard, and
// epiA's VALU/trans fills chain B's MFMA shadow. Register-neutral vs r12
// (accA[2][2]+accB[2][2] = 32 regs = acc[2][4]); same barrier count; per-(fr,cf)
// MFMA chains identical -> u and all hard outputs bitwise identical to r12.
__global__ __launch_bounds__(256, 2)
void sweep_fused_kernel(const float* __restrict__ z, const _Float16* __restrict__ ef,
                        const float* __restrict__ ee, float* __restrict__ Spart,
                        int* __restrict__ cand_cnt, int* __restrict__ cand_idx)
{
    __shared__ _Float16 Bl[2][64 * 256];   // 2 x 32 KB, fragment-major
    __shared__ float Sl[NCODES];           // 16 KB soft accumulator

    const int tid = threadIdx.x;
    const int w = tid >> 6, l = tid & 63;
    const int lg = l >> 4, lc = l & 15;
    const int row0 = blockIdx.x * 128;

    // A fragments: row = row0 + w*32 + fr*16 + lc, k = ksl*32 + lg*8 .. +8 (f32 -> f16)
    half8 af[2][8];
#pragma unroll
    for (int fr = 0; fr < 2; ++fr)
#pragma unroll
    for (int ksl = 0; ksl < 8; ++ksl) {
        const float* zp = z + (size_t)(row0 + w * 32 + fr * 16 + lc) * DDIM + ksl * 32 + lg * 8;
        const float4 v0 = *(const float4*)zp;
        const float4 v1 = *(const float4*)(zp + 4);
        half8 h;
        h[0] = (_Float16)v0.x; h[1] = (_Float16)v0.y; h[2] = (_Float16)v0.z; h[3] = (_Float16)v0.w;
        h[4] = (_Float16)v1.x; h[5] = (_Float16)v1.y; h[6] = (_Float16)v1.z; h[7] = (_Float16)v1.w;
        af[fr][ksl] = h;
    }

    for (int i = tid; i < NCODES; i += 256) Sl[i] = 0.0f;

    // staging: instr it_g = w*8+it = slot (ksl=it_g>>2, cf=it_g&3); lane l fetches
    // global code cf*16+lc at kbytes ksl*64+lg*16 -> LDS it_g*1024 + l*16 (linear).
    int soff[8];
#pragma unroll
    for (int it = 0; it < 8; ++it) {
        const int it_g = w * 8 + it;
        const int ksl = it_g >> 2, cf = it_g & 3;
        soff[it] = (cf * 16 + lc) * 512 + ksl * 64 + lg * 16;
    }
    const char* efb = (const char*)ef;
    char* blb = (char*)&Bl[0][0];

    float pmx[8], pZ[8];
#pragma unroll
    for (int i = 0; i < 8; ++i) { pmx[i] = -1e30f; pZ[i] = 0.0f; }
    int bcnt[8];
#pragma unroll
    for (int i = 0; i < 8; ++i) bcnt[i] = 0;

    // prologue: eev for tile 0 + stage tile 0 into buffer 0
    float eevc[4], eevn[4];
#pragma unroll
    for (int cf = 0; cf < 4; ++cf) eevc[cf] = ee[cf * 16 + lc];
#pragma unroll
    for (int it = 0; it < 8; ++it)
        gload_lds16(efb + soff[it], blb + (w * 8 + it) * 1024);
    __syncthreads();

    for (int s = 0; s < 128; ++s) {
        const int cur = s & 1;
        const int nt = s & 63;
        const int nnt = (s + 1) & 63;

        // next-step eev: issued now, consumed after the barrier (never waited mid-loop)
#pragma unroll
        for (int cf = 0; cf < 4; ++cf) eevn[cf] = ee[nnt * 64 + cf * 16 + lc];

        if (s < 127) {                      // stage next sub-tile into other buffer
            const char* src = efb + ((size_t)nnt << 15);
            char* dst = blb + (cur ^ 1) * 32768;
#pragma unroll
            for (int it = 0; it < 8; ++it)
                gload_lds16(src + soff[it], dst + (w * 8 + it) * 1024);
        }

        // acc init: -0.5*||e||^2  ->  MFMA output u = z.e - ||e||^2/2 = -d'/2
        f32x4 accA[2][2], accB[2][2];
#pragma unroll
        for (int cf = 0; cf < 2; ++cf) {
            const float ehA = -0.5f * eevc[cf];
            const float ehB = -0.5f * eevc[2 + cf];
            accA[0][cf] = (f32x4){ehA, ehA, ehA, ehA};
            accA[1][cf] = (f32x4){ehA, ehA, ehA, ehA};
            accB[0][cf] = (f32x4){ehB, ehB, ehB, ehB};
            accB[1][cf] = (f32x4){ehB, ehB, ehB, ehB};
        }

        const char* bb = blb + cur * 32768 + (l << 4);
        // chain A: cf 0,1 (lane-linear conflict-free reads, immediate offsets)
#pragma unroll
        for (int ksl = 0; ksl < 8; ++ksl) {
#pragma unroll
            for (int cf = 0; cf < 2; ++cf) {
                const half8 b = *(const half8*)(bb + (ksl * 4 + cf) * 1024);
                accA[0][cf] = __builtin_amdgcn_mfma_f32_16x16x32_f16(af[0][ksl], b, accA[0][cf], 0, 0, 0);
                accA[1][cf] = __builtin_amdgcn_mfma_f32_16x16x32_f16(af[1][ksl], b, accA[1][cf], 0, 0, 0);
            }
        }
        // chain B: cf 2,3 — independent of chain A and of epiA
#pragma unroll
        for (int ksl = 0; ksl < 8; ++ksl) {
#pragma unroll
            for (int cf = 0; cf < 2; ++cf) {
                const half8 b = *(const half8*)(bb + (ksl * 4 + 2 + cf) * 1024);
                accB[0][cf] = __builtin_amdgcn_mfma_f32_16x16x32_f16(af[0][ksl], b, accB[0][cf], 0, 0, 0);
                accB[1][cf] = __builtin_amdgcn_mfma_f32_16x16x32_f16(af[1][ksl], b, accB[1][cf], 0, 0, 0);
            }
        }

        if (s < 64) {
            // phase 0, epiA then epiB: exact online (max u, Z); final m identical
#pragma unroll
            for (int fr = 0; fr < 2; ++fr)
#pragma unroll
            for (int reg = 0; reg < 4; ++reg) {
                const int ri = fr * 4 + reg;
                const float u0 = accA[fr][0][reg];
                const float u1 = accA[fr][1][reg];
                const float mloc = fmaxf(u0, u1);
                float m = pmx[ri];
                if (mloc > m - USKIP) {
                    if (mloc > m) { pZ[ri] *= __expf(2.0f * (m - mloc)); m = mloc; pmx[ri] = m; }
                    pZ[ri] += __expf(2.0f * (u0 - m)) + __expf(2.0f * (u1 - m));
                }
            }
#pragma unroll
            for (int fr = 0; fr < 2; ++fr)
#pragma unroll
            for (int reg = 0; reg < 4; ++reg) {
                const int ri = fr * 4 + reg;
                const float u0 = accB[fr][0][reg];
                const float u1 = accB[fr][1][reg];
                const float mloc = fmaxf(u0, u1);
                float m = pmx[ri];
                if (mloc > m - USKIP) {
                    if (mloc > m) { pZ[ri] *= __expf(2.0f * (m - mloc)); m = mloc; pmx[ri] = m; }
                    pZ[ri] += __expf(2.0f * (u0 - m)) + __expf(2.0f * (u1 - m));
                }
            }
        } else {
            // phase 1: u bitwise identical to phase 0; ballot order cf 0,1,2,3 preserved
            float sp[4] = {0.f, 0.f, 0.f, 0.f};
#pragma unroll
            for (int fr = 0; fr < 2; ++fr)
#pragma unroll
            for (int reg = 0; reg < 4; ++reg) {
                const int ri = fr * 4 + reg;
                const float m = pmx[ri], iz = pZ[ri];   // pZ holds 1/Z in phase 1
                const float u0 = accA[fr][0][reg];
                const float u1 = accA[fr][1][reg];
#pragma unroll
                for (int cf = 0; cf < 2; ++cf) {
                    const float u = accA[fr][cf][reg];
                    const bool hit = (u >= m - UMARGIN);   // m = exact phase-0 row max
                    const unsigned long long mk = __ballot(hit);
                    if (mk) {                              // uniform branch, rare
                        const unsigned grp = (unsigned)((mk >> (lg * 16)) & 0xFFFFull);
                        const int slot = bcnt[ri] + __popc(grp & ((1u << lc) - 1u));
                        if (hit && slot < CAND_CAP) {
                            const int rg_ = row0 + w * 32 + fr * 16 + lg * 4 + reg;
                            cand_idx[(size_t)rg_ * CAND_CAP + slot] = nt * 64 + cf * 16 + lc;
                        }
                        bcnt[ri] += __popc(grp);
                    }
                }
                const float umaxA = fmaxf(u0, u1);
                if (umaxA >= m - USKIP) {
                    sp[0] += __expf(2.0f * (u0 - m)) * iz;
                    sp[1] += __expf(2.0f * (u1 - m)) * iz;
                }
            }
#pragma unroll
            for (int fr = 0; fr < 2; ++fr)
#pragma unroll
            for (int reg = 0; reg < 4; ++reg) {
                const int ri = fr * 4 + reg;
                const float m = pmx[ri], iz = pZ[ri];
                const float u2 = accB[fr][0][reg];
                const float u3 = accB[fr][1][reg];
#pragma unroll
                for (int cf = 0; cf < 2; ++cf) {
                    const float u = accB[fr][cf][reg];
                    const bool hit = (u >= m - UMARGIN);
                    const unsigned long long mk = __ballot(hit);
                    if (mk) {
                        const unsigned grp = (unsigned)((mk >> (lg * 16)) & 0xFFFFull);
                        const int slot = bcnt[ri] + __popc(grp & ((1u << lc) - 1u));
                        if (hit && slot < CAND_CAP) {
                            const int rg_ = row0 + w * 32 + fr * 16 + lg * 4 + reg;
                            cand_idx[(size_t)rg_ * CAND_CAP + slot] = nt * 64 + (2 + cf) * 16 + lc;
                        }
                        bcnt[ri] += __popc(grp);
                    }
                }
                const float umaxB = fmaxf(u2, u3);
                if (umaxB >= m - USKIP) {
                    sp[2] += __expf(2.0f * (u2 - m)) * iz;
                    sp[3] += __expf(2.0f * (u3 - m)) * iz;
                }
            }
#pragma unroll
            for (int cf = 0; cf < 4; ++cf) {   // sum across lg, then LDS accumulate
                float v = sp[cf];
                v += __shfl_xor(v, 16, 64);
                v += __shfl_xor(v, 32, 64);
                if (l < 16) atomicAdd(&Sl[nt * 64 + cf * 16 + l], v);
            }
        }

        if (s == 63) {
            // phase boundary: merge (max,Z) across the 16 lanes sharing each row; pZ := 1/Z
#pragma unroll
            for (int ri = 0; ri < 8; ++ri) {
                float m = pmx[ri], Zv = pZ[ri];
#pragma unroll
                for (int off = 1; off < 16; off <<= 1) {
                    const float mo = __shfl_xor(m, off, 64);
                    const float Zo = __shfl_xor(Zv, off, 64);
                    const float mn = fmaxf(m, mo);
                    Zv = Zv * __expf(2.0f * (m - mn)) + Zo * __expf(2.0f * (mo - mn));
                    m = mn;
                }
                pmx[ri] = m;
                pZ[ri] = 1.0f / Zv;
            }
        }

        __syncthreads();   // sole vmcnt drain: staging + eev issued a full phase ago
#pragma unroll
        for (int cf = 0; cf < 4; ++cf) eevc[cf] = eevn[cf];
    }

    // final: per-row candidate counts (plain stores; every row covered once)
    if (lc == 0) {
#pragma unroll
        for (int fr = 0; fr < 2; ++fr)
#pragma unroll
        for (int reg = 0; reg < 4; ++reg)
            cand_cnt[row0 + w * 32 + fr * 16 + lg * 4 + reg] = bcnt[fr * 4 + reg];
    }

    for (int i = tid; i < NCODES; i += 256)
        Spart[(size_t)blockIdx.x * NCODES + i] = Sl[i];
}

// ---------------- refine: exact fp64 argmin over candidates ----------------
__global__ __launch_bounds__(256)
void refine_kernel(const float* __restrict__ z, const float* __restrict__ emb,
                   const int* __restrict__ cand_cnt, const int* __restrict__ cand_idx,
                   float* __restrict__ out_zq, float* __restrict__ out_idx,
                   unsigned int* __restrict__ bincnt, float* __restrict__ rowD)
{
    const int tid = threadIdx.x;
    const int w = tid >> 6, l = tid & 63;
    const int row = blockIdx.x * 4 + w;
    const float4 zv = *(const float4*)(z + (size_t)row * DDIM + l * 4);
    const double z0 = zv.x, z1 = zv.y, z2 = zv.z, z3 = zv.w;
    const int craw = cand_cnt[row];
    const int cnt = craw < 1 ? 1 : (craw > CAND_CAP ? CAND_CAP : craw);
    double dmin = 1e300; int kmin = 0;
    for (int c = 0; c < cnt; ++c) {
        int k = (craw < 1) ? 0 : cand_idx[(size_t)row * CAND_CAP + c];
        k &= (NCODES - 1);
        const float4 ev = *(const float4*)(emb + (size_t)k * DDIM + l * 4);
        const double t0 = z0 - ev.x, t1 = z1 - ev.y, t2 = z2 - ev.z, t3 = z3 - ev.w;
        double s = t0 * t0 + t1 * t1 + t2 * t2 + t3 * t3;
#pragma unroll
        for (int off = 1; off < 64; off <<= 1) s += __shfl_xor(s, off, 64);
        if (s < dmin || (s == dmin && k < kmin)) { dmin = s; kmin = k; }
    }
    const float4 bv = *(const float4*)(emb + (size_t)kmin * DDIM + l * 4);
    *(float4*)(out_zq + (size_t)row * DDIM + l * 4) = bv;   // z + sg(zq - z) == zq
    if (l == 0) {
        out_idx[row] = (float)kmin;
        atomicAdd(&bincnt[kmin], 1u);
        rowD[row] = (float)dmin;                             // dmin == ||z - zq||^2
    }
}

// ---------------- reductions ----------------
__global__ __launch_bounds__(256)
void reduce1_kernel(const float* __restrict__ Spart, const unsigned int* __restrict__ bincnt,
                    const float* __restrict__ rowD,
                    double* __restrict__ te, double* __restrict__ tp, double* __restrict__ tm)
{
    const int k = blockIdx.x * 256 + threadIdx.x;   // grid 16 -> k < 4096
    double s = 0.0;
#pragma unroll 8
    for (int wg = 0; wg < 512; ++wg) s += (double)Spart[(size_t)wg * NCODES + k];
    const double avg = s * (1.0 / 65536.0);
    te[k] = avg * log(avg + 1e-10);
    const double ap = (double)bincnt[k] * (1.0 / 65536.0);
    tp[k] = ap * log(ap + 1e-10);
    double dm = 0.0;
#pragma unroll
    for (int j = 0; j < 16; ++j) dm += (double)rowD[k * 16 + j];
    tm[k] = dm;
}

__global__ __launch_bounds__(256)
void reduce2_kernel(const double* __restrict__ te, const double* __restrict__ tp,
                    const double* __restrict__ tm, float* __restrict__ out)
{
    __shared__ double sa[256], sb[256], sc[256];
    const int tid = threadIdx.x;
    double a = 0.0, b = 0.0, c = 0.0;
    for (int i = tid; i < NCODES; i += 256) { a += te[i]; b += tp[i]; c += tm[i]; }
    sa[tid] = a; sb[tid] = b; sc[tid] = c;
    __syncthreads();
    for (int s = 128; s > 0; s >>= 1) {
        if (tid < s) { sa[tid] += sa[tid + s]; sb[tid] += sb[tid + s]; sc[tid] += sc[tid + s]; }
        __syncthreads();
    }
    if (tid == 0) {
        const double entropy    = -sa[0];
        const double diversity  = log(4096.0) - entropy;
        const double perplexity = exp(-sb[0]);
        const double mse        = sc[0] * (1.0 / 16777216.0);
        const double vq         = 1.25 * mse + 0.1 * diversity;  // 0.25*c + e + 0.1*d, c==e
        out[16777216] = (float)vq;
        out[16777217] = (float)perplexity;
        out[16842754] = (float)diversity;
    }
}

extern "C" void kernel_launch(void* const* d_in, const int* in_sizes, int n_in,
                              void* d_out, int out_size, void* d_ws, size_t ws_size,
                              hipStream_t stream)
{
    const float* z   = (const float*)d_in[0];
    const float* emb = (const float*)d_in[1];
    float* out = (float*)d_out;
    char* ws = (char*)d_ws;
    if (ws_size < (size_t)WS_END) return;   // need ~17.4 MB scratch

    unsigned int* bincnt   = (unsigned int*)(ws + WS_BINCNT);
    int*          cand_cnt = (int*)(ws + WS_CANDCNT);
    float*        Spart    = (float*)(ws + WS_SPART);
    _Float16*     ef16     = (_Float16*)(ws + WS_EF16);
    float*        ee       = (float*)(ws + WS_EE);
    float*        rowD     = (float*)(ws + WS_ROWD);
    int*          cand_idx = (int*)(ws + WS_CANDIDX);
    double*       te       = (double*)(ws + WS_TE);
    double*       tp       = (double*)(ws + WS_TP);
    double*       tm       = (double*)(ws + WS_CANDIDX);  // cand_idx dead after refine

    hipMemsetAsync(d_ws, 0, WS_ZERO_END, stream);   // bincnt only (16 KB)
    hipLaunchKernelGGL(prep_kernel, dim3(NCODES / 4), dim3(256), 0, stream, emb, ef16, ee);
    hipLaunchKernelGGL(sweep_fused_kernel, dim3(NROWS / 128), dim3(256), 0, stream,
                       z, ef16, ee, Spart, cand_cnt, cand_idx);
    hipLaunchKernelGGL(refine_kernel, dim3(NROWS / 4), dim3(256), 0, stream,
                       z, emb, cand_cnt, cand_idx, out, out + 16777218, bincnt, rowD);
    hipLaunchKernelGGL(reduce1_kernel, dim3(16), dim3(256), 0, stream, Spart, bincnt, rowD, te, tp, tm);
    hipLaunchKernelGGL(reduce2_kernel, dim3(1), dim3(256), 0, stream, te, tp, tm, out);
}